// Round 1
// baseline (6941.605 us; speedup 1.0000x reference)
//
#include <hip/hip_runtime.h>
#include <cstdint>
#include <cstddef>

// Problem constants (from reference)
#define BSZ   2
#define T_SEQ 1024
#define D_EMB 1024
#define NH    16
#define NKV   4
#define HS    64
#define NL    6
#define VOCAB 32000
#define FFH   4096

typedef __bf16 bf16x8 __attribute__((ext_vector_type(8)));
typedef float  f32x4  __attribute__((ext_vector_type(4)));

__device__ __forceinline__ unsigned short f2bf(float f) {
    // round-to-nearest-even f32 -> bf16 (finite inputs only)
    unsigned u = __float_as_uint(f);
    u += 0x7fffu + ((u >> 16) & 1u);
    return (unsigned short)(u >> 16);
}

// ---------------- embedding: x[b,t,:] = tok_emb[tok] + pos_emb[t] ----------------
__global__ void embed_kernel(const int* __restrict__ tok,
                             const float* __restrict__ tok_emb,
                             const float* __restrict__ pos_emb,
                             float* __restrict__ x) {
    int row = blockIdx.x;               // b*T + t
    int t   = row & (T_SEQ - 1);
    int tk  = tok[row];
    int tid = threadIdx.x;              // 256 threads * float4 = 1024
    f32x4 te = ((const f32x4*)(tok_emb + (size_t)tk * D_EMB))[tid];
    f32x4 pe = ((const f32x4*)(pos_emb + (size_t)t  * D_EMB))[tid];
    ((f32x4*)(x + (size_t)row * D_EMB))[tid] = te + pe;
}

// ---------------- layernorm: out = (x-mu)*rsqrt(var+eps)*g + b ----------------
__global__ void ln_kernel(const float* __restrict__ x,
                          const float* __restrict__ g,
                          const float* __restrict__ b,
                          float* __restrict__ out) {
    int row = blockIdx.x;
    int tid = threadIdx.x;
    f32x4 v = ((const f32x4*)(x + (size_t)row * D_EMB))[tid];
    float s  = v.x + v.y + v.z + v.w;
    float s2 = v.x*v.x + v.y*v.y + v.z*v.z + v.w*v.w;
#pragma unroll
    for (int o = 32; o; o >>= 1) { s += __shfl_down(s, o); s2 += __shfl_down(s2, o); }
    __shared__ float sm[8];
    int wave = tid >> 6, lane = tid & 63;
    if (lane == 0) { sm[wave] = s; sm[4 + wave] = s2; }
    __syncthreads();
    s  = sm[0] + sm[1] + sm[2] + sm[3];
    s2 = sm[4] + sm[5] + sm[6] + sm[7];
    float mu   = s * (1.0f / D_EMB);
    float var  = s2 * (1.0f / D_EMB) - mu * mu;
    float rstd = rsqrtf(var + 1e-5f);
    f32x4 gv = ((const f32x4*)g)[tid];
    f32x4 bv = ((const f32x4*)b)[tid];
    f32x4 o4 = (v - mu) * rstd * gv + bv;
    ((f32x4*)(out + (size_t)row * D_EMB))[tid] = o4;
}

// ---------------- bf16-MFMA GEMM: C = A(MxK,f32) @ B(KxN,f32) [+bias][+Res][ReLU] ----------------
// 128x128 tile / block (256 thr = 4 waves, each wave 64x64 = 4x4 mfma 16x16x32 tiles), BK=32.
// f32 global -> convert -> LDS bf16. A stored [128][40] m-major; B stored transposed [128][40] n-major
// so both fragment reads are contiguous 16B (ds_read_b128), stride 40 bf16 = 80 B (16B-aligned, 2-way banks = free).
template<int BIAS, int RES, int RELU>
__global__ __launch_bounds__(256)
void gemm_kernel(const float* __restrict__ A, const float* __restrict__ B,
                 const float* __restrict__ bias, const float* __restrict__ Res,
                 float* __restrict__ C, int M, int N, int K) {
    constexpr int BK  = 32;
    constexpr int LDA = 40;
    __shared__ unsigned short Asm[128 * LDA];
    __shared__ unsigned short Bsm[128 * LDA];

    const int tid  = threadIdx.x;
    const int lane = tid & 63;
    const int wave = tid >> 6;
    const int quad = lane >> 4;
    const int l16  = lane & 15;
    const int m0   = blockIdx.x * 128;
    const int n0   = blockIdx.y * 128;
    const int wm   = (wave >> 1) * 64;
    const int wn   = (wave & 1) * 64;

    f32x4 acc[4][4] = {};

    for (int k0 = 0; k0 < K; k0 += BK) {
        __syncthreads();   // previous iteration's fragment reads must finish
        // ---- stage A tile: 128 rows x 32 k  (1024 float4 chunks / 256 thr) ----
#pragma unroll
        for (int i = 0; i < 4; ++i) {
            int chunk = i * 256 + tid;
            int row = chunk >> 3, kc = (chunk & 7) << 2;
            f32x4 av = *(const f32x4*)(A + (size_t)(m0 + row) * K + k0 + kc);
            union { unsigned short h[4]; uint2 u; } tmp;
            tmp.h[0] = f2bf(av.x); tmp.h[1] = f2bf(av.y);
            tmp.h[2] = f2bf(av.z); tmp.h[3] = f2bf(av.w);
            *(uint2*)&Asm[row * LDA + kc] = tmp.u;
        }
        // ---- stage B tile transposed: 32 k x 128 n -> Bsm[n][k] ----
#pragma unroll
        for (int i = 0; i < 4; ++i) {
            int chunk = i * 256 + tid;
            int krow = chunk >> 5, nc = (chunk & 31) << 2;
            f32x4 bv = *(const f32x4*)(B + (size_t)(k0 + krow) * N + n0 + nc);
            Bsm[(nc + 0) * LDA + krow] = f2bf(bv.x);
            Bsm[(nc + 1) * LDA + krow] = f2bf(bv.y);
            Bsm[(nc + 2) * LDA + krow] = f2bf(bv.z);
            Bsm[(nc + 3) * LDA + krow] = f2bf(bv.w);
        }
        __syncthreads();
        // ---- fragments + 16 MFMA ----
        bf16x8 af[4], bfr[4];
#pragma unroll
        for (int mi = 0; mi < 4; ++mi)
            af[mi] = *(const bf16x8*)&Asm[(wm + mi * 16 + l16) * LDA + quad * 8];
#pragma unroll
        for (int ni = 0; ni < 4; ++ni)
            bfr[ni] = *(const bf16x8*)&Bsm[(wn + ni * 16 + l16) * LDA + quad * 8];
#pragma unroll
        for (int mi = 0; mi < 4; ++mi)
#pragma unroll
            for (int ni = 0; ni < 4; ++ni)
                acc[mi][ni] = __builtin_amdgcn_mfma_f32_16x16x32_bf16(af[mi], bfr[ni], acc[mi][ni], 0, 0, 0);
    }

    // ---- epilogue: D[row=quad*4+r][col=lane&15] ----
#pragma unroll
    for (int mi = 0; mi < 4; ++mi) {
#pragma unroll
        for (int ni = 0; ni < 4; ++ni) {
            int col = n0 + wn + ni * 16 + l16;
            float bv = BIAS ? bias[col] : 0.0f;
#pragma unroll
            for (int r = 0; r < 4; ++r) {
                int row = m0 + wm + mi * 16 + quad * 4 + r;
                float val = acc[mi][ni][r] + bv;
                if (RES)  val += Res[(size_t)row * N + col];
                if (RELU) val = fmaxf(val, 0.0f);
                C[(size_t)row * N + col] = val;
            }
        }
    }
}

// ---------------- causal GQA flash attention (f32) ----------------
// block = (qb, h, b): 64 q-rows, 256 thr; thread (r = tid>>2, c = tid&3) owns q-row r, dims [c*16, c*16+16)
__global__ __launch_bounds__(256)
void attn_kernel(const float* __restrict__ Q, const float* __restrict__ Kt,
                 const float* __restrict__ Vt, float* __restrict__ Y) {
    constexpr int LP = 68;                  // padded row stride (floats): 16B-aligned
    __shared__ float Ks[64 * LP];
    __shared__ float Vs[64 * LP];
    __shared__ float Ps[64 * LP];

    const int qb = blockIdx.x, h = blockIdx.y, b = blockIdx.z;
    const int kvh = h >> 2;                 // REP = 4
    const int tid = threadIdx.x;
    const int r = tid >> 2, c = tid & 3;
    const int q0 = qb * 64;

    const float* qrow = Q + (size_t)(b * T_SEQ + q0 + r) * D_EMB + h * HS;
    f32x4 q4[16];
#pragma unroll
    for (int j = 0; j < 16; ++j) q4[j] = *(const f32x4*)(qrow + j * 4);

    float o[16];
#pragma unroll
    for (int d = 0; d < 16; ++d) o[d] = 0.f;
    float m = -1e30f, l = 0.f;

    for (int kt = 0; kt <= qb; ++kt) {
        int k0 = kt * 64;
        __syncthreads();                    // protect K/V overwrite
#pragma unroll
        for (int i = 0; i < 4; ++i) {
            int idx = i * 256 + tid;
            int row = idx >> 4, d4 = (idx & 15) << 2;
            size_t gofs = (size_t)(b * T_SEQ + k0 + row) * (NKV * HS) + kvh * HS + d4;
            *(f32x4*)&Ks[row * LP + d4] = *(const f32x4*)(Kt + gofs);
            *(f32x4*)&Vs[row * LP + d4] = *(const f32x4*)(Vt + gofs);
        }
        __syncthreads();

        float s[16];
#pragma unroll
        for (int kk = 0; kk < 16; ++kk) {
            int k = c * 16 + kk;
            const f32x4* krow = (const f32x4*)&Ks[k * LP];
            float a = 0.f;
#pragma unroll
            for (int j = 0; j < 16; ++j) {
                f32x4 kv = krow[j];
                a += q4[j].x * kv.x + q4[j].y * kv.y + q4[j].z * kv.z + q4[j].w * kv.w;
            }
            a *= 0.125f;                    // HS^-0.5
            if (k0 + k > q0 + r) a = -1e30f;
            s[kk] = a;
        }
        float mx = s[0];
#pragma unroll
        for (int kk = 1; kk < 16; ++kk) mx = fmaxf(mx, s[kk]);
        mx = fmaxf(mx, __shfl_xor(mx, 1));
        mx = fmaxf(mx, __shfl_xor(mx, 2));
        float mnew  = fmaxf(m, mx);
        float alpha = __expf(m - mnew);
        float ls = 0.f;
#pragma unroll
        for (int kk = 0; kk < 16; ++kk) { s[kk] = __expf(s[kk] - mnew); ls += s[kk]; }
        ls += __shfl_xor(ls, 1);
        ls += __shfl_xor(ls, 2);
        l = l * alpha + ls;
        m = mnew;
#pragma unroll
        for (int kk = 0; kk < 16; ++kk) Ps[r * LP + c * 16 + kk] = s[kk];
        // Ps row is produced & consumed by the same wave (lanes 4r..4r+3) -> no barrier needed
#pragma unroll
        for (int d = 0; d < 16; ++d) o[d] *= alpha;
        for (int k = 0; k < 64; ++k) {
            float p = Ps[r * LP + k];
            const f32x4* vrow = (const f32x4*)&Vs[k * LP + c * 16];
#pragma unroll
            for (int dj = 0; dj < 4; ++dj) {
                f32x4 vv = vrow[dj];
                o[dj * 4 + 0] += p * vv.x; o[dj * 4 + 1] += p * vv.y;
                o[dj * 4 + 2] += p * vv.z; o[dj * 4 + 3] += p * vv.w;
            }
        }
    }
    float inv = 1.0f / l;
    float* yrow = Y + (size_t)(b * T_SEQ + q0 + r) * D_EMB + h * HS + c * 16;
#pragma unroll
    for (int dj = 0; dj < 4; ++dj) {
        f32x4 ov;
        ov.x = o[dj * 4 + 0] * inv; ov.y = o[dj * 4 + 1] * inv;
        ov.z = o[dj * 4 + 2] * inv; ov.w = o[dj * 4 + 3] * inv;
        *(f32x4*)(yrow + dj * 4) = ov;
    }
}

// ---------------- launch ----------------
extern "C" void kernel_launch(void* const* d_in, const int* in_sizes, int n_in,
                              void* d_out, int out_size, void* d_ws, size_t ws_size,
                              hipStream_t stream) {
    (void)in_sizes; (void)n_in; (void)out_size; (void)ws_size;
    const int*   tokens  = (const int*)  d_in[0];
    const float* tok_emb = (const float*)d_in[1];
    const float* pos_emb = (const float*)d_in[2];
    const float* ln1_g   = (const float*)d_in[3];
    const float* ln1_b   = (const float*)d_in[4];
    const float* Wq      = (const float*)d_in[5];
    const float* Wk      = (const float*)d_in[6];
    const float* Wv      = (const float*)d_in[7];
    const float* Wo      = (const float*)d_in[8];
    const float* bo      = (const float*)d_in[9];
    const float* ln2_g   = (const float*)d_in[10];
    const float* ln2_b   = (const float*)d_in[11];
    const float* W1      = (const float*)d_in[12];
    const float* b1      = (const float*)d_in[13];
    const float* W2      = (const float*)d_in[14];
    const float* b2      = (const float*)d_in[15];
    const float* lnf_g   = (const float*)d_in[16];
    const float* lnf_b   = (const float*)d_in[17];
    const float* Wlm     = (const float*)d_in[18];
    const float* blm     = (const float*)d_in[19];
    float* out = (float*)d_out;

    const int M = BSZ * T_SEQ;   // 2048

    char* p = (char*)d_ws;
    float* x    = (float*)p; p += (size_t)M * D_EMB * 4;
    float* hbuf = (float*)p; p += (size_t)M * D_EMB * 4;
    float* qb   = (float*)p; p += (size_t)M * D_EMB * 4;
    float* kb   = (float*)p; p += (size_t)M * NKV * HS * 4;
    float* vb   = (float*)p; p += (size_t)M * NKV * HS * 4;
    float* yb   = (float*)p; p += (size_t)M * D_EMB * 4;
    float* ffn  = (float*)p; p += (size_t)M * FFH * 4;

    embed_kernel<<<M, 256, 0, stream>>>(tokens, tok_emb, pos_emb, x);

    for (int l = 0; l < NL; ++l) {
        ln_kernel<<<M, 256, 0, stream>>>(x, ln1_g + l * D_EMB, ln1_b + l * D_EMB, hbuf);
        gemm_kernel<0,0,0><<<dim3(M/128, D_EMB/128), 256, 0, stream>>>(
            hbuf, Wq + (size_t)l * D_EMB * D_EMB, nullptr, nullptr, qb, M, D_EMB, D_EMB);
        gemm_kernel<0,0,0><<<dim3(M/128, (NKV*HS)/128), 256, 0, stream>>>(
            hbuf, Wk + (size_t)l * D_EMB * NKV * HS, nullptr, nullptr, kb, M, NKV * HS, D_EMB);
        gemm_kernel<0,0,0><<<dim3(M/128, (NKV*HS)/128), 256, 0, stream>>>(
            hbuf, Wv + (size_t)l * D_EMB * NKV * HS, nullptr, nullptr, vb, M, NKV * HS, D_EMB);
        attn_kernel<<<dim3(T_SEQ/64, NH, BSZ), 256, 0, stream>>>(qb, kb, vb, yb);
        gemm_kernel<1,1,0><<<dim3(M/128, D_EMB/128), 256, 0, stream>>>(
            yb, Wo + (size_t)l * D_EMB * D_EMB, bo + l * D_EMB, x, x, M, D_EMB, D_EMB);
        ln_kernel<<<M, 256, 0, stream>>>(x, ln2_g + l * D_EMB, ln2_b + l * D_EMB, hbuf);
        gemm_kernel<1,0,1><<<dim3(M/128, FFH/128), 256, 0, stream>>>(
            hbuf, W1 + (size_t)l * D_EMB * FFH, b1 + l * FFH, nullptr, ffn, M, FFH, D_EMB);
        gemm_kernel<1,1,0><<<dim3(M/128, D_EMB/128), 256, 0, stream>>>(
            ffn, W2 + (size_t)l * FFH * D_EMB, b2 + l * D_EMB, x, x, M, D_EMB, FFH);
    }
    ln_kernel<<<M, 256, 0, stream>>>(x, lnf_g, lnf_b, hbuf);
    gemm_kernel<1,0,0><<<dim3(M/128, VOCAB/128), 256, 0, stream>>>(
        hbuf, Wlm, blm, nullptr, out, M, VOCAB, D_EMB);
}